// Round 3
// baseline (709.577 us; speedup 1.0000x reference)
//
#include <hip/hip_runtime.h>
#include <hip/hip_bf16.h>
#include <math.h>

using frag8 = __attribute__((ext_vector_type(8))) short;
using f32x4 = __attribute__((ext_vector_type(4))) float;

#define BM 256
#define BN 256

typedef const __attribute__((address_space(1))) unsigned char glb_u8;
typedef __attribute__((address_space(3))) unsigned char lds_u8;

__device__ __forceinline__ float b2f(unsigned short v) {
    union { unsigned u; float f; } x; x.u = ((unsigned)v) << 16; return x.f;
}
__device__ __forceinline__ unsigned short f2b(float f) {
    union { float f; unsigned u; } x; x.f = f;
    unsigned u = x.u;
    u += 0x7fffu + ((u >> 16) & 1u);   // RNE
    return (unsigned short)(u >> 16);
}

// ---------------- cast fp32 -> bf16 (vectorized) ----------------
__global__ __launch_bounds__(256) void cast_kernel(const float* __restrict__ in,
                                                   unsigned short* __restrict__ out, long n) {
    long i = ((long)blockIdx.x * 256 + threadIdx.x) * 8;
    if (i >= n) return;
    float4 a = *(const float4*)(in + i);
    float4 b = *(const float4*)(in + i + 4);
    struct alignas(16) U8 { unsigned short s[8]; } o;
    o.s[0] = f2b(a.x); o.s[1] = f2b(a.y); o.s[2] = f2b(a.z); o.s[3] = f2b(a.w);
    o.s[4] = f2b(b.x); o.s[5] = f2b(b.y); o.s[6] = f2b(b.z); o.s[7] = f2b(b.w);
    *(U8*)(out + i) = o;
}

// ---------------- transpose + cast: in (R x C) fp32 -> out (C x R) bf16 ----------------
__global__ void transpose_cast(const float* __restrict__ in, unsigned short* __restrict__ out,
                               int R, int Ccols) {
    __shared__ float tile[32][33];
    int bx = blockIdx.x * 32;   // col base in input
    int by = blockIdx.y * 32;   // row base in input
    int tx = threadIdx.x, ty = threadIdx.y;
    for (int r = ty; r < 32; r += 8)
        tile[r][tx] = in[(size_t)(by + r) * Ccols + bx + tx];
    __syncthreads();
    for (int r = ty; r < 32; r += 8)
        out[(size_t)(bx + r) * R + by + tx] = f2b(tile[tx][r]);
}

// ---------------- bf16 MFMA GEMM: C[M,N] = A[M,K] * Bt[N,K]^T ----------------
// Ring-4 of BK=32 K-units x fine 2-phase interleave (T3+T4+T5).
//  - LDS: 4 slots x 32 KB (A 16KB + B 16KB per unit) = 128 KiB.
//  - Unit u: phA = {stage A(u+3) [2 loads], read a_hi(u), barrier, 16 MFMA, barrier};
//            phB = {stage B(u+3), vmcnt(8) fence + barrier (publishes u+1, staged
//            2 units = ~4 phases earlier -> cover >= HBM latency), read a_lo/b(u+1),
//            16 MFMA, barrier}. Steady state: 12 loads outstanding at fence, drain
//            exactly one unit; never vmcnt(0) mid-loop (tail: vm4 then vm0).
//  - b-frags ping-pong with static parity (2x-unrolled body; rule #20).
//  - VGPR budget: frags 16x4=64 + addr ~12; acc 128 AGPR -> ~205/256, no spill.
//  - LDS swizzle for BK=32 (64B rows, 4 chunks): chunk' = chunk ^ ((row>>1)&3),
//    applied on the pre-swizzled global SOURCE (global_load_lds dest is linear) and
//    on the ds_read side -> uniform 2 lanes/bank (free, m136).
// mode 0: store fp32 to Cf
// mode 1: N==3072 split epilogue (block-uniform segment, BN=256 divides 1024):
//         V=gelu, Q=gelu, Lam=lb+(1-lb)*sigmoid, all bf16.
__global__ __launch_bounds__(512, 2) void gemm_bf16(
    const unsigned short* __restrict__ A, const unsigned short* __restrict__ Bt,
    int M, int N, int K, int mode,
    float* __restrict__ Cf,
    unsigned short* __restrict__ Vp, unsigned short* __restrict__ Qp,
    unsigned short* __restrict__ Lp, const float* __restrict__ lb) {
    __shared__ __align__(16) char smem[131072];   // 4 slots x 32 KB

    const int tid = threadIdx.x;
    const int lane = tid & 63;
    const int lane16 = lane & 15;
    const int quad = lane >> 4;
    const int wave = tid >> 6;
    const int wm = wave >> 2;        // 0..1 -> 128-row half of C
    const int wn = wave & 3;         // 0..3 -> 64-col slice of C

    // XCD-aware bijective swizzle (nwg % 8 == 0 for both launches)
    const int nbx = N / BN;
    const int nwg = (int)gridDim.x;
    const int sw = ((int)blockIdx.x & 7) * (nwg >> 3) + ((int)blockIdx.x >> 3);
    const long m0 = (long)(sw / nbx) * BM;
    const long n0 = (long)(sw % nbx) * BN;
    const long K2 = (long)K * 2;

    // ---- staging source offsets (shared by A and B) ----
    // LDS offset o = tid*16 (+8192): row r = o>>6, chunk c = (o>>4)&3;
    // logical chunk c0 = c ^ ((r>>1)&3)  [second load: r+128, same (r>>1)&3 mod 4].
    const int c0x16 = (((tid & 3) ^ ((tid >> 3) & 3)) << 4);
    const long srcO0 = (long)(tid >> 2) * K2 + c0x16;
    const long srcO1 = srcO0 + 128 * K2;
    const char* Ab = (const char*)A + m0 * K2;
    const char* Bb = (const char*)Bt + n0 * K2;
    const int dst0 = tid * 16;

    // ---- ds_read bases (bytes within a slot); frag index folds to +1024 steps ----
    const int swz = ((quad ^ ((lane16 >> 1) & 3)) << 4);
    const int aRd = wm * 8192 + lane16 * 64 + swz;             // A: [0, 16384)
    const int bRd = 16384 + wn * 4096 + lane16 * 64 + swz;     // B: [16384, 32768)

    f32x4 acc[8][4];
#pragma unroll
    for (int i = 0; i < 8; ++i)
#pragma unroll
        for (int j = 0; j < 4; ++j) acc[i][j] = (f32x4){0.f, 0.f, 0.f, 0.f};
    frag8 aL[4], aH[4], bE[4], bO[4];

#define STAGE_A(u_) do { int _sb = ((u_) & 3) << 15; long _kb = (long)(u_) * 64; \
        __builtin_amdgcn_global_load_lds((glb_u8*)(Ab + srcO0 + _kb), \
            (lds_u8*)(smem + _sb + dst0), 16, 0, 0); \
        __builtin_amdgcn_global_load_lds((glb_u8*)(Ab + srcO1 + _kb), \
            (lds_u8*)(smem + _sb + 8192 + dst0), 16, 0, 0); \
    } while (0)
#define STAGE_B(u_) do { int _sb = ((u_) & 3) << 15; long _kb = (long)(u_) * 64; \
        __builtin_amdgcn_global_load_lds((glb_u8*)(Bb + srcO0 + _kb), \
            (lds_u8*)(smem + _sb + 16384 + dst0), 16, 0, 0); \
        __builtin_amdgcn_global_load_lds((glb_u8*)(Bb + srcO1 + _kb), \
            (lds_u8*)(smem + _sb + 24576 + dst0), 16, 0, 0); \
    } while (0)
#define RD_ALO(D, u_) do { const char* _p = smem + (((u_) & 3) << 15) + aRd; \
        D[0] = *(const frag8*)(_p);        D[1] = *(const frag8*)(_p + 1024); \
        D[2] = *(const frag8*)(_p + 2048); D[3] = *(const frag8*)(_p + 3072); } while (0)
#define RD_AHI(D, u_) do { const char* _p = smem + (((u_) & 3) << 15) + aRd + 4096; \
        D[0] = *(const frag8*)(_p);        D[1] = *(const frag8*)(_p + 1024); \
        D[2] = *(const frag8*)(_p + 2048); D[3] = *(const frag8*)(_p + 3072); } while (0)
#define RD_B(D, u_) do { const char* _p = smem + (((u_) & 3) << 15) + bRd; \
        D[0] = *(const frag8*)(_p);        D[1] = *(const frag8*)(_p + 1024); \
        D[2] = *(const frag8*)(_p + 2048); D[3] = *(const frag8*)(_p + 3072); } while (0)
#define MM4(AF, BF, RO) do { \
        _Pragma("unroll") \
        for (int _m = 0; _m < 4; ++_m) \
            _Pragma("unroll") \
            for (int _n = 0; _n < 4; ++_n) \
                acc[(RO) + _m][_n] = __builtin_amdgcn_mfma_f32_16x16x32_bf16( \
                    AF[_m], BF[_n], acc[(RO) + _m][_n], 0, 0, 0); \
    } while (0)
#define FENCE(x_) do { \
        if ((x_) < NT - 3)       asm volatile("s_waitcnt vmcnt(8)" ::: "memory"); \
        else if ((x_) == NT - 3) asm volatile("s_waitcnt vmcnt(4)" ::: "memory"); \
        else                     asm volatile("s_waitcnt vmcnt(0)" ::: "memory"); \
    } while (0)
#define BARR __builtin_amdgcn_s_barrier()
#define PRIO1 __builtin_amdgcn_s_setprio(1)
#define PRIO0 __builtin_amdgcn_s_setprio(0)

    const int NT = K >> 5;   // 32-wide K-units (NT >= 4, even)

    // ---- prologue: fill 3 units; drain only unit 0; first reads ----
    STAGE_A(0); STAGE_B(0); STAGE_A(1); STAGE_B(1); STAGE_A(2); STAGE_B(2);
    asm volatile("s_waitcnt vmcnt(8)" ::: "memory");
    BARR;
    RD_ALO(aL, 0); RD_B(bE, 0);

    for (int u = 0; u < NT; u += 2) {
        // ======== unit u (even parity: bE) ========
        // phA
        if (u + 3 < NT) STAGE_A(u + 3);
        RD_AHI(aH, u);
        BARR;
        PRIO1; MM4(aL, bE, 0); PRIO0;
        BARR;
        // phB
        if (u + 3 < NT) STAGE_B(u + 3);
        {   // u+1 < NT always (u <= NT-2)
            FENCE(u); BARR;
            RD_ALO(aL, u + 1); RD_B(bO, u + 1);
        }
        PRIO1; MM4(aH, bE, 4); PRIO0;
        BARR;
        // ======== unit u+1 (odd parity: bO) ========
        // phA
        if (u + 4 < NT) STAGE_A(u + 4);
        RD_AHI(aH, u + 1);
        BARR;
        PRIO1; MM4(aL, bO, 0); PRIO0;
        BARR;
        // phB
        if (u + 4 < NT) STAGE_B(u + 4);
        if (u + 2 < NT) {
            FENCE(u + 1); BARR;
            RD_ALO(aL, u + 2); RD_B(bE, u + 2);
        }
        PRIO1; MM4(aH, bO, 4); PRIO0;
        BARR;
    }
#undef STAGE_A
#undef STAGE_B
#undef RD_ALO
#undef RD_AHI
#undef RD_B
#undef MM4
#undef FENCE
#undef BARR
#undef PRIO1
#undef PRIO0

    if (mode == 0) {
#pragma unroll
        for (int mf = 0; mf < 8; ++mf)
#pragma unroll
            for (int nf = 0; nf < 4; ++nf) {
                long col = n0 + wn * 64 + nf * 16 + lane16;
#pragma unroll
                for (int r = 0; r < 4; ++r) {
                    long row = m0 + wm * 128 + mf * 16 + quad * 4 + r;
                    Cf[row * N + col] = acc[mf][nf][r];
                }
            }
    } else {
        // block-uniform segment: BN=256 divides 1024, so each block is in one segment
        const int seg = (int)(n0 >> 10);            // 0=V, 1=Q, 2=Lam
        const int cbase = (int)(n0 & 1023) + wn * 64;
        unsigned short* dst = (seg == 0) ? Vp : (seg == 1 ? Qp : Lp);
#pragma unroll
        for (int mf = 0; mf < 8; ++mf)
#pragma unroll
            for (int nf = 0; nf < 4; ++nf) {
                int col = cbase + nf * 16 + lane16;
#pragma unroll
                for (int r = 0; r < 4; ++r) {
                    long row = m0 + wm * 128 + mf * 16 + quad * 4 + r;
                    float v = acc[mf][nf][r];
                    float res;
                    if (seg < 2) {
                        // tanh-form gelu: x * sigmoid(1.5958*x*(1+0.044715 x^2))
                        float u = 1.59576912f * v * (1.0f + 0.044715f * v * v);
                        res = v / (1.0f + __expf(-u));
                    } else {
                        float sg = 1.0f / (1.0f + __expf(-v));
                        float l = lb[col];
                        res = l + (1.0f - l) * sg;
                    }
                    dst[row * 1024 + col] = f2b(res);
                }
            }
    }
}

// ---------------- scan phase 1: per-(chain,chunk) local state + decay product ----------------
__global__ __launch_bounds__(256) void scan_phase1(
    const unsigned short* __restrict__ lam, const unsigned short* __restrict__ V,
    float* __restrict__ Sl, float* __restrict__ P, int L) {
    int cid = blockIdx.x * 256 + threadIdx.x;  // 0..4095
    int c = blockIdx.y;
    int bi = cid >> 9, h = cid & 511;
    float s00 = 0, s01 = 0, s10 = 0, s11 = 0, p0 = 1.f, p1 = 1.f;
    int t0 = c * L;
    const unsigned* lamp = (const unsigned*)lam;
    const unsigned* vp = (const unsigned*)V;
    for (int t = t0; t < t0 + L; ++t) {
        long idx = (long)(t * 8 + bi) * 512 + h;
        unsigned lu = lamp[idx], vu = vp[idx];
        float la0 = b2f((unsigned short)lu), la1 = b2f((unsigned short)(lu >> 16));
        float v0 = b2f((unsigned short)vu), v1 = b2f((unsigned short)(vu >> 16));
        float k0 = 1.f - la0, k1 = 1.f - la1;
        s00 = fmaf(la0, s00, k0 * v0); s01 = fmaf(la0, s01, k0 * v1);
        s10 = fmaf(la1, s10, k1 * v0); s11 = fmaf(la1, s11, k1 * v1);
        p0 *= la0; p1 *= la1;
    }
    long base = (long)c * 4096 + cid;
    ((float4*)Sl)[base] = make_float4(s00, s01, s10, s11);
    ((float2*)P)[base] = make_float2(p0, p1);
}

// ---------------- scan phase 2: sequential combine over chunks ----------------
__global__ __launch_bounds__(256) void scan_phase2(
    const float* __restrict__ Sl, const float* __restrict__ P,
    float* __restrict__ Sini, int C) {
    int idx = blockIdx.x * 256 + threadIdx.x;  // 0..16383
    int cid = idx >> 2, ij = idx & 3, i = (idx >> 1) & 1;
    float s = 0.f;
    for (int c = 0; c < C; ++c) {
        long base = (long)c * 4096 + cid;
        Sini[base * 4 + ij] = s;
        s = fmaf(P[base * 2 + i], s, Sl[base * 4 + ij]);
    }
}

// ---------------- scan phase 3: replay with seeded state, emit o ----------------
__global__ __launch_bounds__(256) void scan_phase3(
    const unsigned short* __restrict__ lam, const unsigned short* __restrict__ V,
    const unsigned short* __restrict__ Q, const float* __restrict__ Sini,
    unsigned short* __restrict__ o, int L) {
    int cid = blockIdx.x * 256 + threadIdx.x;
    int c = blockIdx.y;
    int bi = cid >> 9, h = cid & 511;
    float4 si = ((const float4*)Sini)[(long)c * 4096 + cid];
    float s00 = si.x, s01 = si.y, s10 = si.z, s11 = si.w;
    int t0 = c * L;
    const unsigned* lamp = (const unsigned*)lam;
    const unsigned* vp = (const unsigned*)V;
    const unsigned* qp = (const unsigned*)Q;
    unsigned* op = (unsigned*)o;
    for (int t = t0; t < t0 + L; ++t) {
        long idx = (long)(t * 8 + bi) * 512 + h;
        unsigned lu = lamp[idx], vu = vp[idx], qu = qp[idx];
        float la0 = b2f((unsigned short)lu), la1 = b2f((unsigned short)(lu >> 16));
        float v0 = b2f((unsigned short)vu), v1 = b2f((unsigned short)(vu >> 16));
        float q0 = b2f((unsigned short)qu), q1 = b2f((unsigned short)(qu >> 16));
        float k0 = 1.f - la0, k1 = 1.f - la1;
        s00 = fmaf(la0, s00, k0 * v0); s01 = fmaf(la0, s01, k0 * v1);
        s10 = fmaf(la1, s10, k1 * v0); s11 = fmaf(la1, s11, k1 * v1);
        float o0 = q0 * s00 + q1 * s10;
        float o1 = q0 * s01 + q1 * s11;
        op[idx] = (unsigned)f2b(o0) | ((unsigned)f2b(o1) << 16);
    }
}

extern "C" void kernel_launch(void* const* d_in, const int* in_sizes, int n_in,
                              void* d_out, int out_size, void* d_ws, size_t ws_size,
                              hipStream_t stream) {
    const float* x = (const float*)d_in[0];
    const float* lb = (const float*)d_in[1];
    const float* W_in = (const float*)d_in[2];
    const float* W_out = (const float*)d_in[3];
    float* out = (float*)d_out;

    const int n = 4096, b = 8, d = 1024;
    const long NB = (long)n * b;   // 32768 rows
    const int C = 64, L = 64;      // chunks x chunk length (C*L == n)

    char* ws = (char*)d_ws;
    size_t off = 0;
    auto alloc = [&](size_t bytes) -> char* {
        char* p = ws + off;
        off += (bytes + 255) & ~(size_t)255;
        return p;
    };
    unsigned short* xb   = (unsigned short*)alloc(NB * d * 2);          // reused as o after GEMM1
    unsigned short* Wint = (unsigned short*)alloc((size_t)3 * d * d * 2);
    unsigned short* Wot  = (unsigned short*)alloc((size_t)d * d * 2);
    unsigned short* Vb   = (unsigned short*)alloc(NB * d * 2);
    unsigned short* Qb   = (unsigned short*)alloc(NB * d * 2);
    unsigned short* Lb   = (unsigned short*)alloc(NB * d * 2);
    float* Sl   = (float*)alloc((size_t)C * 4096 * 4 * 4);
    float* P    = (float*)alloc((size_t)C * 4096 * 2 * 4);
    float* Sini = (float*)alloc((size_t)C * 4096 * 4 * 4);

    // 1) cast x -> bf16
    cast_kernel<<<dim3((unsigned)((NB * d) / (256 * 8))), 256, 0, stream>>>(x, xb, NB * d);
    // 2) transpose+cast weights (so GEMM B operand is K-contiguous)
    transpose_cast<<<dim3(3 * d / 32, d / 32), dim3(32, 8), 0, stream>>>(W_in, Wint, d, 3 * d);
    transpose_cast<<<dim3(d / 32, d / 32), dim3(32, 8), 0, stream>>>(W_out, Wot, d, d);
    // 3) GEMM1 + fused activations -> V, Q, lam (bf16); 256x256 tiles, 512 threads
    const int nwg1 = (3 * d / BN) * (int)(NB / BM);   // 12 * 128 = 1536 (%8==0)
    gemm_bf16<<<dim3(nwg1), 512, 0, stream>>>(
        xb, Wint, (int)NB, 3 * d, d, 1, nullptr, Vb, Qb, Lb, lb);
    // 4) chunked scan
    scan_phase1<<<dim3(16, C), 256, 0, stream>>>(Lb, Vb, Sl, P, L);
    scan_phase2<<<dim3(64), 256, 0, stream>>>(Sl, P, Sini, C);
    unsigned short* ob = xb;  // xb dead after GEMM1; reuse as o
    scan_phase3<<<dim3(16, C), 256, 0, stream>>>(Lb, Vb, Qb, Sini, ob, L);
    // 5) GEMM2 -> fp32 output
    const int nwg2 = (d / BN) * (int)(NB / BM);       // 4 * 128 = 512 (%8==0)
    gemm_bf16<<<dim3(nwg2), 512, 0, stream>>>(
        ob, Wot, (int)NB, d, d, 0, out, nullptr, nullptr, nullptr, nullptr);
}

// Round 6
// 656.676 us; speedup vs baseline: 1.0806x; 1.0806x over previous
//
#include <hip/hip_runtime.h>
#include <hip/hip_bf16.h>
#include <math.h>

using frag8 = __attribute__((ext_vector_type(8))) short;
using f32x4 = __attribute__((ext_vector_type(4))) float;

#define BM 256
#define BN 256

typedef const __attribute__((address_space(1))) unsigned char glb_u8;
typedef __attribute__((address_space(3))) unsigned char lds_u8;

__device__ __forceinline__ float b2f(unsigned short v) {
    union { unsigned u; float f; } x; x.u = ((unsigned)v) << 16; return x.f;
}
__device__ __forceinline__ unsigned short f2b(float f) {
    union { float f; unsigned u; } x; x.f = f;
    unsigned u = x.u;
    u += 0x7fffu + ((u >> 16) & 1u);   // RNE
    return (unsigned short)(u >> 16);
}

// ---------------- cast fp32 -> bf16 (vectorized) ----------------
__global__ __launch_bounds__(256) void cast_kernel(const float* __restrict__ in,
                                                   unsigned short* __restrict__ out, long n) {
    long i = ((long)blockIdx.x * 256 + threadIdx.x) * 8;
    if (i >= n) return;
    float4 a = *(const float4*)(in + i);
    float4 b = *(const float4*)(in + i + 4);
    struct alignas(16) U8 { unsigned short s[8]; } o;
    o.s[0] = f2b(a.x); o.s[1] = f2b(a.y); o.s[2] = f2b(a.z); o.s[3] = f2b(a.w);
    o.s[4] = f2b(b.x); o.s[5] = f2b(b.y); o.s[6] = f2b(b.z); o.s[7] = f2b(b.w);
    *(U8*)(out + i) = o;
}

// ---------------- transpose + cast: in (R x C) fp32 -> out (C x R) bf16 ----------------
__global__ void transpose_cast(const float* __restrict__ in, unsigned short* __restrict__ out,
                               int R, int Ccols) {
    __shared__ float tile[32][33];
    int bx = blockIdx.x * 32;   // col base in input
    int by = blockIdx.y * 32;   // row base in input
    int tx = threadIdx.x, ty = threadIdx.y;
    for (int r = ty; r < 32; r += 8)
        tile[r][tx] = in[(size_t)(by + r) * Ccols + bx + tx];
    __syncthreads();
    for (int r = ty; r < 32; r += 8)
        out[(size_t)(bx + r) * R + by + tx] = f2b(tile[tx][r]);
}

// ---------------- bf16 MFMA GEMM: C[M,N] = A[M,K] * Bt[N,K]^T ----------------
// R1 ring-4 structure (best measured: 676 TF on GEMM1). K consumed in 32-wide
// units; LDS holds 4 units (A 16KB + B 16KB each = 128 KiB). Each iteration
// stages unit t+3 (4x global_load_lds 16B), computes unit t as two 16-MFMA
// clusters under setprio(1), then ONE counted s_waitcnt vmcnt(8) + barrier:
// 12 loads (3 units) stay in flight across the barrier, only the oldest unit
// drains -> never vmcnt(0) in steady state. LDS rows pair-interleaved (two 64B
// rows per 128B line) with chunk-XOR swizzle (applied on the pre-swizzled
// global SOURCE; read side same XOR) -> 0 bank conflicts measured.
// mode 0: store fp32 to Cf
// mode 1: N==3072 split epilogue (block-uniform segment): V=gelu, Q=gelu,
//         Lam=lb+(1-lb)*sigmoid, all bf16.
__global__ __launch_bounds__(512, 2) void gemm_bf16(
    const unsigned short* __restrict__ A, const unsigned short* __restrict__ Bt,
    int M, int N, int K, int mode,
    float* __restrict__ Cf,
    unsigned short* __restrict__ Vp, unsigned short* __restrict__ Qp,
    unsigned short* __restrict__ Lp, const float* __restrict__ lb) {
    __shared__ __align__(16) char smem[131072];   // 4 units x (16KB A + 16KB B)

    const int tid = threadIdx.x;
    const int lane16 = tid & 15;
    const int quad = (tid >> 4) & 3;
    const int wave = tid >> 6;
    const int wm = wave >> 2;        // 0..1 -> 128-row half
    const int wn = wave & 3;         // 0..3 -> 64-col slice

    // XCD-aware bijective swizzle (nwg % 8 == 0 for both our launches)
    const int nbx = N / BN;
    const int nwg = (int)gridDim.x;
    const int sw = ((int)blockIdx.x & 7) * (nwg >> 3) + ((int)blockIdx.x >> 3);
    const long m0 = (long)(sw / nbx) * BM;
    const long n0 = (long)(sw % nbx) * BN;
    const long K2 = (long)K * 2;

    // ---- staging addresses (identical pattern for A and B) ----
    // load L in {0,1} writes LDS bytes [L*8192 + tid*16, +16) of the unit region.
    // line = off/128, chunk c = (off/16)&7; logical chunk c0 = c ^ (line&7);
    // line i holds rows {2i, 2i+1}: c0 = rowpar*4 + kblk (kblk = 8-elem group of k).
    const int c0 = (tid & 7) ^ ((tid >> 3) & 7);
    long srcL0, srcL1; int dstL0, dstL1;
    {
        const int kk2 = (c0 & 3) << 4;                      // byte offset of k-group
        const int r0 = ((tid >> 3) << 1) + (c0 >> 2);       // rows 0..127
        const int r1 = ((64 + (tid >> 3)) << 1) + (c0 >> 2);// rows 128..255
        srcL0 = (long)r0 * K2 + kk2;
        srcL1 = (long)r1 * K2 + kk2;
        dstL0 = tid * 16;
        dstL1 = 8192 + tid * 16;
    }
    const char* Ab = (const char*)A + m0 * K2;
    const char* Bb = (const char*)Bt + n0 * K2;

    // ---- fragment read offsets within a unit (bytes), constant across K ----
    int offA[8], offB[4];
#pragma unroll
    for (int mf = 0; mf < 8; ++mf) {
        int row = wm * 128 + mf * 16 + lane16;
        int line = row >> 1;
        int c = (((row & 1) << 2) | quad) ^ (line & 7);
        offA[mf] = line * 128 + c * 16;
    }
#pragma unroll
    for (int nf = 0; nf < 4; ++nf) {
        int row = wn * 64 + nf * 16 + lane16;
        int line = row >> 1;
        int c = (((row & 1) << 2) | quad) ^ (line & 7);
        offB[nf] = 16384 + line * 128 + c * 16;
    }

    f32x4 acc[8][4];
#pragma unroll
    for (int i = 0; i < 8; ++i)
#pragma unroll
        for (int j = 0; j < 4; ++j) acc[i][j] = (f32x4){0.f, 0.f, 0.f, 0.f};

#define STAGE(u) do { \
        char* ldb = smem + ((u) & 3) * 32768; \
        long kb = (long)(u) * 64; \
        __builtin_amdgcn_global_load_lds((glb_u8*)(Ab + srcL0 + kb), (lds_u8*)(ldb + dstL0), 16, 0, 0); \
        __builtin_amdgcn_global_load_lds((glb_u8*)(Ab + srcL1 + kb), (lds_u8*)(ldb + dstL1), 16, 0, 0); \
        __builtin_amdgcn_global_load_lds((glb_u8*)(Bb + srcL0 + kb), (lds_u8*)(ldb + 16384 + dstL0), 16, 0, 0); \
        __builtin_amdgcn_global_load_lds((glb_u8*)(Bb + srcL1 + kb), (lds_u8*)(ldb + 16384 + dstL1), 16, 0, 0); \
    } while (0)

    const int NT = K >> 5;   // 32-wide K-units
    // prologue: fill 3 units of the ring; drain only the oldest
    STAGE(0); STAGE(1); STAGE(2);
    asm volatile("s_waitcnt vmcnt(8)" ::: "memory");
    __builtin_amdgcn_s_barrier();

    for (int t = 0; t < NT; ++t) {
        if (t + 3 < NT) STAGE(t + 3);
        const char* ub = smem + (t & 3) * 32768;
        frag8 bfr[4], af[4];
#pragma unroll
        for (int nf = 0; nf < 4; ++nf) bfr[nf] = *(const frag8*)(ub + offB[nf]);
#pragma unroll
        for (int mf = 0; mf < 4; ++mf) af[mf] = *(const frag8*)(ub + offA[mf]);
        __builtin_amdgcn_s_setprio(1);
#pragma unroll
        for (int mf = 0; mf < 4; ++mf)
#pragma unroll
            for (int nf = 0; nf < 4; ++nf)
                acc[mf][nf] = __builtin_amdgcn_mfma_f32_16x16x32_bf16(af[mf], bfr[nf], acc[mf][nf], 0, 0, 0);
        __builtin_amdgcn_s_setprio(0);
#pragma unroll
        for (int mf = 0; mf < 4; ++mf) af[mf] = *(const frag8*)(ub + offA[4 + mf]);
        __builtin_amdgcn_s_setprio(1);
#pragma unroll
        for (int mf = 0; mf < 4; ++mf)
#pragma unroll
            for (int nf = 0; nf < 4; ++nf)
                acc[4 + mf][nf] = __builtin_amdgcn_mfma_f32_16x16x32_bf16(af[mf], bfr[nf], acc[4 + mf][nf], 0, 0, 0);
        __builtin_amdgcn_s_setprio(0);
        // counted fence: guarantee unit t+1 landed; keep 2 units in flight
        if (t < NT - 3)       { asm volatile("s_waitcnt vmcnt(8)" ::: "memory"); }
        else if (t == NT - 3) { asm volatile("s_waitcnt vmcnt(4)" ::: "memory"); }
        else if (t == NT - 2) { asm volatile("s_waitcnt vmcnt(0)" ::: "memory"); }
        __builtin_amdgcn_s_barrier();
    }
#undef STAGE

    if (mode == 0) {
#pragma unroll
        for (int mf = 0; mf < 8; ++mf)
#pragma unroll
            for (int nf = 0; nf < 4; ++nf) {
                long col = n0 + wn * 64 + nf * 16 + lane16;
#pragma unroll
                for (int r = 0; r < 4; ++r) {
                    long row = m0 + wm * 128 + mf * 16 + quad * 4 + r;
                    Cf[row * N + col] = acc[mf][nf][r];
                }
            }
    } else {
        // block-uniform segment: BN=256 divides 1024, so each block is in one segment
        const int seg = (int)(n0 >> 10);            // 0=V, 1=Q, 2=Lam
        const int cbase = (int)(n0 & 1023) + wn * 64;
        unsigned short* dst = (seg == 0) ? Vp : (seg == 1 ? Qp : Lp);
#pragma unroll
        for (int mf = 0; mf < 8; ++mf)
#pragma unroll
            for (int nf = 0; nf < 4; ++nf) {
                int col = cbase + nf * 16 + lane16;
#pragma unroll
                for (int r = 0; r < 4; ++r) {
                    long row = m0 + wm * 128 + mf * 16 + quad * 4 + r;
                    float v = acc[mf][nf][r];
                    float res;
                    if (seg < 2) {
                        // tanh-form gelu: x * sigmoid(1.5958*x*(1+0.044715 x^2))
                        float u = 1.59576912f * v * (1.0f + 0.044715f * v * v);
                        res = v / (1.0f + __expf(-u));
                    } else {
                        float sg = 1.0f / (1.0f + __expf(-v));
                        float l = lb[col];
                        res = l + (1.0f - l) * sg;
                    }
                    dst[row * 1024 + col] = f2b(res);
                }
            }
    }
}

// ---------------- scan phase 1: per-(chain,chunk) local state + decay product ----------------
// Constexpr trip count + unroll-8: the 2 loads/iter are independent of the FMA
// recurrence, so unrolling batches 16 loads in flight per thread instead of
// serializing ~500-cycle latencies. FP order unchanged (same fmaf sequence).
__global__ __launch_bounds__(256) void scan_phase1(
    const unsigned short* __restrict__ lam, const unsigned short* __restrict__ V,
    float* __restrict__ Sl, float* __restrict__ P) {
    constexpr int L = 64;
    int cid = blockIdx.x * 256 + threadIdx.x;  // 0..4095
    int c = blockIdx.y;
    int bi = cid >> 9, h = cid & 511;
    float s00 = 0, s01 = 0, s10 = 0, s11 = 0, p0 = 1.f, p1 = 1.f;
    const int t0 = c * L;
    const unsigned* lamp = (const unsigned*)lam;
    const unsigned* vp = (const unsigned*)V;
    const long base0 = ((long)t0 * 8 + bi) * 512 + h;
#pragma unroll 8
    for (int tt = 0; tt < L; ++tt) {
        long idx = base0 + (long)tt * 4096;
        unsigned lu = lamp[idx], vu = vp[idx];
        float la0 = b2f((unsigned short)lu), la1 = b2f((unsigned short)(lu >> 16));
        float v0 = b2f((unsigned short)vu), v1 = b2f((unsigned short)(vu >> 16));
        float k0 = 1.f - la0, k1 = 1.f - la1;
        s00 = fmaf(la0, s00, k0 * v0); s01 = fmaf(la0, s01, k0 * v1);
        s10 = fmaf(la1, s10, k1 * v0); s11 = fmaf(la1, s11, k1 * v1);
        p0 *= la0; p1 *= la1;
    }
    long base = (long)c * 4096 + cid;
    ((float4*)Sl)[base] = make_float4(s00, s01, s10, s11);
    ((float2*)P)[base] = make_float2(p0, p1);
}

// ---------------- scan phase 2: sequential combine over chunks ----------------
// Unroll-8 batches the (independent-address) P/Sl loads across the s-recurrence.
__global__ __launch_bounds__(256) void scan_phase2(
    const float* __restrict__ Sl, const float* __restrict__ P,
    float* __restrict__ Sini) {
    constexpr int C = 64;
    int idx = blockIdx.x * 256 + threadIdx.x;  // 0..16383
    int cid = idx >> 2, ij = idx & 3, i = (idx >> 1) & 1;
    float s = 0.f;
#pragma unroll 8
    for (int c = 0; c < C; ++c) {
        long base = (long)c * 4096 + cid;
        Sini[base * 4 + ij] = s;
        s = fmaf(P[base * 2 + i], s, Sl[base * 4 + ij]);
    }
}

// ---------------- scan phase 3: replay with seeded state, emit o ----------------
// Same unroll treatment as phase 1 (3 loads + 1 store per iter, 24 loads in
// flight per unrolled group).
__global__ __launch_bounds__(256) void scan_phase3(
    const unsigned short* __restrict__ lam, const unsigned short* __restrict__ V,
    const unsigned short* __restrict__ Q, const float* __restrict__ Sini,
    unsigned short* __restrict__ o) {
    constexpr int L = 64;
    int cid = blockIdx.x * 256 + threadIdx.x;
    int c = blockIdx.y;
    int bi = cid >> 9, h = cid & 511;
    float4 si = ((const float4*)Sini)[(long)c * 4096 + cid];
    float s00 = si.x, s01 = si.y, s10 = si.z, s11 = si.w;
    const int t0 = c * L;
    const unsigned* lamp = (const unsigned*)lam;
    const unsigned* vp = (const unsigned*)V;
    const unsigned* qp = (const unsigned*)Q;
    unsigned* op = (unsigned*)o;
    const long base0 = ((long)t0 * 8 + bi) * 512 + h;
#pragma unroll 8
    for (int tt = 0; tt < L; ++tt) {
        long idx = base0 + (long)tt * 4096;
        unsigned lu = lamp[idx], vu = vp[idx], qu = qp[idx];
        float la0 = b2f((unsigned short)lu), la1 = b2f((unsigned short)(lu >> 16));
        float v0 = b2f((unsigned short)vu), v1 = b2f((unsigned short)(vu >> 16));
        float q0 = b2f((unsigned short)qu), q1 = b2f((unsigned short)(qu >> 16));
        float k0 = 1.f - la0, k1 = 1.f - la1;
        s00 = fmaf(la0, s00, k0 * v0); s01 = fmaf(la0, s01, k0 * v1);
        s10 = fmaf(la1, s10, k1 * v0); s11 = fmaf(la1, s11, k1 * v1);
        float o0 = q0 * s00 + q1 * s10;
        float o1 = q0 * s01 + q1 * s11;
        op[idx] = (unsigned)f2b(o0) | ((unsigned)f2b(o1) << 16);
    }
}

extern "C" void kernel_launch(void* const* d_in, const int* in_sizes, int n_in,
                              void* d_out, int out_size, void* d_ws, size_t ws_size,
                              hipStream_t stream) {
    const float* x = (const float*)d_in[0];
    const float* lb = (const float*)d_in[1];
    const float* W_in = (const float*)d_in[2];
    const float* W_out = (const float*)d_in[3];
    float* out = (float*)d_out;

    const int n = 4096, b = 8, d = 1024;
    const long NB = (long)n * b;   // 32768 rows
    const int C = 64;              // chunks (chunk length 64; C*L == n)

    char* ws = (char*)d_ws;
    size_t off = 0;
    auto alloc = [&](size_t bytes) -> char* {
        char* p = ws + off;
        off += (bytes + 255) & ~(size_t)255;
        return p;
    };
    unsigned short* xb   = (unsigned short*)alloc(NB * d * 2);          // reused as o after GEMM1
    unsigned short* Wint = (unsigned short*)alloc((size_t)3 * d * d * 2);
    unsigned short* Wot  = (unsigned short*)alloc((size_t)d * d * 2);
    unsigned short* Vb   = (unsigned short*)alloc(NB * d * 2);
    unsigned short* Qb   = (unsigned short*)alloc(NB * d * 2);
    unsigned short* Lb   = (unsigned short*)alloc(NB * d * 2);
    float* Sl   = (float*)alloc((size_t)C * 4096 * 4 * 4);
    float* P    = (float*)alloc((size_t)C * 4096 * 2 * 4);
    float* Sini = (float*)alloc((size_t)C * 4096 * 4 * 4);

    // 1) cast x -> bf16
    cast_kernel<<<dim3((unsigned)((NB * d) / (256 * 8))), 256, 0, stream>>>(x, xb, NB * d);
    // 2) transpose+cast weights (so GEMM B operand is K-contiguous)
    transpose_cast<<<dim3(3 * d / 32, d / 32), dim3(32, 8), 0, stream>>>(W_in, Wint, d, 3 * d);
    transpose_cast<<<dim3(d / 32, d / 32), dim3(32, 8), 0, stream>>>(W_out, Wot, d, d);
    // 3) GEMM1 + fused activations -> V, Q, lam (bf16); 256x256 tiles, 512 threads
    const int nwg1 = (3 * d / BN) * (int)(NB / BM);   // 12 * 128 = 1536 (%8==0)
    gemm_bf16<<<dim3(nwg1), 512, 0, stream>>>(
        xb, Wint, (int)NB, 3 * d, d, 1, nullptr, Vb, Qb, Lb, lb);
    // 4) chunked scan
    scan_phase1<<<dim3(16, C), 256, 0, stream>>>(Lb, Vb, Sl, P);
    scan_phase2<<<dim3(64), 256, 0, stream>>>(Sl, P, Sini);
    unsigned short* ob = xb;  // xb dead after GEMM1; reuse as o
    scan_phase3<<<dim3(16, C), 256, 0, stream>>>(Lb, Vb, Qb, Sini, ob);
    // 5) GEMM2 -> fp32 output
    const int nwg2 = (d / BN) * (int)(NB / BM);       // 4 * 128 = 512 (%8==0)
    gemm_bf16<<<dim3(nwg2), 512, 0, stream>>>(
        ob, Wot, (int)NB, d, d, 0, out, nullptr, nullptr, nullptr, nullptr);
}